// Round 6
// baseline (24.038 us; speedup 1.0000x reference)
//
#include <hip/hip_runtime.h>
#include <math.h>

#define B_ 128
#define K_ 2048
#define TEMP_ 0.07f
#define EPS_ 1e-12f
#define NBLK_ 1024   // 64 i-pairs * 16 j-groups

// ---------------------------------------------------------------------------
// k_pairs v6: 2 i-rows per block, 8 j's per block.
// Grid 1024: blk = ip*16 + jg;  i0 = ip*2, i1 = ip*2+1;  j = jg*8 + wave*2
// + (lane>>5).  Each 32-lane group owns one j (k split 32 ways, 16 float4
// iters/lane); the j-row load b and b^2 sums are SHARED across both i's:
// 19 ops per element for 2 pairs (vs 2x10), and j-row global traffic halves.
//
// Math identical to v5 per (i,j) (w-form, raw b, norm folded at epilogue):
//   a = x_i/||x_i||, g = 1+a^3 (LDS);  w = b*g; p = a*b; q = p*p
//   du=S(aw) uu=S(w2) sab=S(p) saq=S(aq) sqq=S(q2) sqb=S(qb)  per i
//   sbb=S(b2)                                                 shared
//   ds = du/max(sqrt(uu),eps)/T;  c = 1/max(sqrt(sbb),eps)
//   dn = (c*saq+sab)/max(sqrt(c^2*sqq+2c*sqb+sbb),eps)/T
// Partials per (i,jg): sum_j ds, sum_j (e^ds + 3 e^dn).
// ---------------------------------------------------------------------------
__global__ __launch_bounds__(256, 4) void k_pairs(const float* __restrict__ feat,
                                                  float* __restrict__ part) {
    const int blk = blockIdx.x;
    const int ip = blk >> 4;
    const int jg = blk & 15;
    const int i0 = ip * 2;
    const int tid = threadIdx.x;
    const int wave = tid >> 6, lane = tid & 63;
    const int l32 = lane & 31;

    __shared__ float sa0[K_], sg0[K_], sa1[K_], sg1[K_];
    __shared__ float wsum[4];
    __shared__ float sp[4][4];

    // ---- stage both i-rows: waves 0-1 -> i0, waves 2-3 -> i1 ----
    {
        const int half = tid >> 7;            // 0: i0, 1: i1
        const int t = tid & 127;
        const float4* row4 = reinterpret_cast<const float4*>(feat + (size_t)(i0 + half) * K_);
        float4 v0 = row4[t];
        float4 v1 = row4[t + 128];
        float4 v2 = row4[t + 256];
        float4 v3 = row4[t + 384];
        float ss = v0.x*v0.x + v0.y*v0.y + v0.z*v0.z + v0.w*v0.w
                 + v1.x*v1.x + v1.y*v1.y + v1.z*v1.z + v1.w*v1.w
                 + v2.x*v2.x + v2.y*v2.y + v2.z*v2.z + v2.w*v2.w
                 + v3.x*v3.x + v3.y*v3.y + v3.z*v3.z + v3.w*v3.w;
#pragma unroll
        for (int o = 1; o < 64; o <<= 1) ss += __shfl_xor(ss, o, 64);
        if (lane == 0) wsum[wave] = ss;
        __syncthreads();
        const float tot = wsum[half * 2] + wsum[half * 2 + 1];
        const float rn = 1.0f / fmaxf(sqrtf(tot), EPS_);

        float4* a4w = reinterpret_cast<float4*>(half ? sa1 : sa0);
        float4* g4w = reinterpret_cast<float4*>(half ? sg1 : sg0);
#define STAGE(V, IDX)                                                   \
        {                                                               \
            float4 a, g;                                                \
            a.x = (V).x * rn; a.y = (V).y * rn;                         \
            a.z = (V).z * rn; a.w = (V).w * rn;                         \
            g.x = 1.0f + a.x * a.x * a.x; g.y = 1.0f + a.y * a.y * a.y; \
            g.z = 1.0f + a.z * a.z * a.z; g.w = 1.0f + a.w * a.w * a.w; \
            a4w[IDX] = a; g4w[IDX] = g;                                 \
        }
        STAGE(v0, t)
        STAGE(v1, t + 128)
        STAGE(v2, t + 256)
        STAGE(v3, t + 384)
#undef STAGE
    }
    __syncthreads();

    const int j = jg * 8 + wave * 2 + (lane >> 5);
    const float4* bj = reinterpret_cast<const float4*>(feat + (size_t)j * K_);
    const float4* a04 = reinterpret_cast<const float4*>(sa0);
    const float4* g04 = reinterpret_cast<const float4*>(sg0);
    const float4* a14 = reinterpret_cast<const float4*>(sa1);
    const float4* g14 = reinterpret_cast<const float4*>(sg1);

    float du0 = 0.f, uu0 = 0.f, sab0 = 0.f, saq0 = 0.f, sqq0 = 0.f, sqb0 = 0.f;
    float du1 = 0.f, uu1 = 0.f, sab1 = 0.f, saq1 = 0.f, sqq1 = 0.f, sqb1 = 0.f;
    float sbb = 0.f;

#pragma unroll 4
    for (int it = 0; it < 16; ++it) {
        const int idx = it * 32 + l32;
        const float4 b  = bj[idx];
        const float4 a0 = a04[idx];
        const float4 g0 = g04[idx];
        const float4 a1 = a14[idx];
        const float4 g1 = g14[idx];
#define ACC1(AX, GX, BX, DU, UU, SAB, SAQ, SQQ, SQB)   \
        {                                              \
            const float w = (BX) * (GX);               \
            DU  = fmaf((AX), w, DU);                   \
            UU  = fmaf(w, w, UU);                      \
            const float p = (AX) * (BX);               \
            SAB += p;                                  \
            const float q = p * p;                     \
            SAQ = fmaf((AX), q, SAQ);                  \
            SQQ = fmaf(q, q, SQQ);                     \
            SQB = fmaf(q, (BX), SQB);                  \
        }
#define ACCE(C)                                                              \
        ACC1(a0.C, g0.C, b.C, du0, uu0, sab0, saq0, sqq0, sqb0)              \
        ACC1(a1.C, g1.C, b.C, du1, uu1, sab1, saq1, sqq1, sqb1)              \
        sbb = fmaf(b.C, b.C, sbb);
        ACCE(x)
        ACCE(y)
        ACCE(z)
        ACCE(w)
#undef ACCE
#undef ACC1
    }

    // ---- 5-step butterfly over the 32-lane group (13 sums) ----
#pragma unroll
    for (int o = 1; o < 32; o <<= 1) {
        du0  += __shfl_xor(du0,  o, 64);
        uu0  += __shfl_xor(uu0,  o, 64);
        sab0 += __shfl_xor(sab0, o, 64);
        saq0 += __shfl_xor(saq0, o, 64);
        sqq0 += __shfl_xor(sqq0, o, 64);
        sqb0 += __shfl_xor(sqb0, o, 64);
        du1  += __shfl_xor(du1,  o, 64);
        uu1  += __shfl_xor(uu1,  o, 64);
        sab1 += __shfl_xor(sab1, o, 64);
        saq1 += __shfl_xor(saq1, o, 64);
        sqq1 += __shfl_xor(sqq1, o, 64);
        sqb1 += __shfl_xor(sqb1, o, 64);
        sbb  += __shfl_xor(sbb,  o, 64);
    }

    // ---- per-j epilogue, both i's ----
    const float inv_t = 1.0f / TEMP_;
    const float c  = 1.0f / fmaxf(sqrtf(sbb), EPS_);
    const float c2 = c * c, tc = 2.0f * c;

    const float ds0 = du0 / fmaxf(sqrtf(uu0), EPS_) * inv_t;
    const float dv0 = fmaf(c, saq0, sab0);
    const float vv0 = fmaf(c2, sqq0, fmaf(tc, sqb0, sbb));
    const float dn0 = dv0 / fmaxf(sqrtf(vv0), EPS_) * inv_t;
    float s1_0 = ds0;
    float s2_0 = __expf(ds0) + 3.0f * __expf(dn0);

    const float ds1 = du1 / fmaxf(sqrtf(uu1), EPS_) * inv_t;
    const float dv1 = fmaf(c, saq1, sab1);
    const float vv1 = fmaf(c2, sqq1, fmaf(tc, sqb1, sbb));
    const float dn1 = dv1 / fmaxf(sqrtf(vv1), EPS_) * inv_t;
    float s1_1 = ds1;
    float s2_1 = __expf(ds1) + 3.0f * __expf(dn1);

    // combine the wave's 2 j's (halves at xor 32)
    s1_0 += __shfl_xor(s1_0, 32, 64);
    s2_0 += __shfl_xor(s2_0, 32, 64);
    s1_1 += __shfl_xor(s1_1, 32, 64);
    s2_1 += __shfl_xor(s2_1, 32, 64);

    if (lane == 0) {
        sp[wave][0] = s1_0; sp[wave][1] = s2_0;
        sp[wave][2] = s1_1; sp[wave][3] = s2_1;
    }
    __syncthreads();
    if (tid == 0) {
        const int i1 = i0 + 1;
        float a0 = 0.f, b0 = 0.f, a1 = 0.f, b1 = 0.f;
#pragma unroll
        for (int w = 0; w < 4; ++w) {
            a0 += sp[w][0]; b0 += sp[w][1];
            a1 += sp[w][2]; b1 += sp[w][3];
        }
        part[(i0 * 16 + jg) * 2 + 0] = a0;
        part[(i0 * 16 + jg) * 2 + 1] = b0;
        part[(i1 * 16 + jg) * 2 + 0] = a1;
        part[(i1 * 16 + jg) * 2 + 1] = b1;
    }
}

// ---------------------------------------------------------------------------
// k_final: thread i combines its 16 group-partials, computes
// contrib_i = (1/B) * sum_j d_self - log(denom_i), reduces over i.
// ---------------------------------------------------------------------------
__global__ __launch_bounds__(128) void k_final(const float* __restrict__ part,
                                               float* __restrict__ out) {
    const int i = threadIdx.x;
    float s1 = 0.0f, s2 = 0.0f;
#pragma unroll
    for (int q = 0; q < 16; ++q) {
        s1 += part[(i * 16 + q) * 2 + 0];
        s2 += part[(i * 16 + q) * 2 + 1];
    }
    float c = s1 * (1.0f / B_) - __logf(s2);
#pragma unroll
    for (int o = 1; o < 64; o <<= 1) c += __shfl_xor(c, o, 64);
    __shared__ float wsum[2];
    const int wave = i >> 6, lane = i & 63;
    if (lane == 0) wsum[wave] = c;
    __syncthreads();
    if (i == 0) out[0] = -(wsum[0] + wsum[1]) * (1.0f / B_);
}

extern "C" void kernel_launch(void* const* d_in, const int* in_sizes, int n_in,
                              void* d_out, int out_size, void* d_ws, size_t ws_size,
                              hipStream_t stream) {
    const float* feat = (const float*)d_in[0];
    float* part = (float*)d_ws;              // 128*16*2 floats
    float* out = (float*)d_out;

    k_pairs<<<NBLK_, 256, 0, stream>>>(feat, part);
    k_final<<<1, 128, 0, stream>>>(part, out);
}

// Round 7
// 20.599 us; speedup vs baseline: 1.1669x; 1.1669x over previous
//
#include <hip/hip_runtime.h>
#include <math.h>

#define B_ 128
#define K_ 2048
#define TEMP_ 0.07f
#define EPS_ 1e-12f
#define NBLK_ 1024   // 128 i * 8 j-groups

// ---------------------------------------------------------------------------
// k_pairs v7: v5 structure (16-lane group per j) + two-pass direct v-form.
// Grid 1024: blk = i*8 + jg. 256 threads = 4 waves; each wave owns 4 j's,
// one per 16-lane group. Lane accumulates a k-slice (stride-16 float4).
//
// Pass 1: sbb = S(b^2)  -> c = 1/max(||b||,eps)   (1 op/elem, 4 shuffles)
// Pass 2 (b reloaded, L1/L2-hot):
//   w = b*g;        du = S(a w), uu = S(w^2)      (self path)
//   p = a*b; q=p*p; v = c*q + b                   (other path, DIRECT form)
//   dv = S(a v), vv = S(v^2)
//   ds = du/max(sqrt(uu),eps)/T;  dn = dv/max(sqrt(vv),eps)/T
// 9 ops/elem (vs 10), 5 reduce sums (vs 7), simpler epilogue.
// Partials per (i,jg): sum_j ds, sum_j (e^ds + 3 e^dn).
// ---------------------------------------------------------------------------
__global__ __launch_bounds__(256, 4) void k_pairs(const float* __restrict__ feat,
                                                  float* __restrict__ part) {
    const int blk = blockIdx.x;
    const int i = blk >> 3;
    const int jg = blk & 7;
    const int tid = threadIdx.x;
    const int wave = tid >> 6, lane = tid & 63;
    const int s = lane & 15;      // sublane within 16-lane group
    const int grp = lane >> 4;    // group 0..3 -> which j

    __shared__ float sa[K_];
    __shared__ float sg[K_];
    __shared__ float wsum[4];

    // ---- stage i-row: block-local norm, then a and g=1+a^3 into LDS ----
    {
        const float4* fi4 = reinterpret_cast<const float4*>(feat + (size_t)i * K_);
        float4 v0 = fi4[tid];
        float4 v1 = fi4[tid + 256];
        float ss = v0.x * v0.x + v0.y * v0.y + v0.z * v0.z + v0.w * v0.w
                 + v1.x * v1.x + v1.y * v1.y + v1.z * v1.z + v1.w * v1.w;
#pragma unroll
        for (int o = 1; o < 64; o <<= 1) ss += __shfl_xor(ss, o, 64);
        if (lane == 0) wsum[wave] = ss;
        __syncthreads();
        const float tot = wsum[0] + wsum[1] + wsum[2] + wsum[3];
        const float rn = 1.0f / fmaxf(sqrtf(tot), EPS_);

        float4* a4w = reinterpret_cast<float4*>(sa);
        float4* g4w = reinterpret_cast<float4*>(sg);
#define STAGE(V, IDX)                                                   \
        {                                                               \
            float4 a, g;                                                \
            a.x = (V).x * rn; a.y = (V).y * rn;                         \
            a.z = (V).z * rn; a.w = (V).w * rn;                         \
            g.x = 1.0f + a.x * a.x * a.x; g.y = 1.0f + a.y * a.y * a.y; \
            g.z = 1.0f + a.z * a.z * a.z; g.w = 1.0f + a.w * a.w * a.w; \
            a4w[IDX] = a; g4w[IDX] = g;                                 \
        }
        STAGE(v0, tid)
        STAGE(v1, tid + 256)
#undef STAGE
    }
    __syncthreads();

    const int j = jg * 16 + wave * 4 + grp;
    const float4* bj = reinterpret_cast<const float4*>(feat + (size_t)j * K_);
    const float4* a4 = reinterpret_cast<const float4*>(sa);
    const float4* g4 = reinterpret_cast<const float4*>(sg);

    // ---- pass 1: sbb ----
    float sbb = 0.f;
#pragma unroll 8
    for (int c = 0; c < 32; ++c) {
        const float4 b = bj[c * 16 + s];
        sbb = fmaf(b.x, b.x, sbb);
        sbb = fmaf(b.y, b.y, sbb);
        sbb = fmaf(b.z, b.z, sbb);
        sbb = fmaf(b.w, b.w, sbb);
    }
#pragma unroll
    for (int o = 1; o < 16; o <<= 1) sbb += __shfl_xor(sbb, o, 64);
    const float cc = 1.0f / fmaxf(sqrtf(sbb), EPS_);

    // ---- pass 2: du, uu, dv, vv with v = cc*q + b formed directly ----
    float du = 0.f, uu = 0.f, dv = 0.f, vv = 0.f;
#pragma unroll 8
    for (int c = 0; c < 32; ++c) {
        const int idx = c * 16 + s;        // same for all 4 groups: LDS broadcast
        const float4 a = a4[idx];
        const float4 g = g4[idx];
        const float4 b = bj[idx];
#define ACC1(AX, GX, BX)                             \
        {                                            \
            const float w = (BX) * (GX);             \
            du = fmaf((AX), w, du);                  \
            uu = fmaf(w, w, uu);                     \
            const float p = (AX) * (BX);             \
            const float q = p * p;                   \
            const float v = fmaf(cc, q, (BX));       \
            dv = fmaf((AX), v, dv);                  \
            vv = fmaf(v, v, vv);                     \
        }
        ACC1(a.x, g.x, b.x)
        ACC1(a.y, g.y, b.y)
        ACC1(a.z, g.z, b.z)
        ACC1(a.w, g.w, b.w)
#undef ACC1
    }

    // ---- 4-step butterfly within the 16-lane group (4 sums) ----
#pragma unroll
    for (int o = 1; o < 16; o <<= 1) {
        du += __shfl_xor(du, o, 64);
        uu += __shfl_xor(uu, o, 64);
        dv += __shfl_xor(dv, o, 64);
        vv += __shfl_xor(vv, o, 64);
    }

    // ---- per-j epilogue ----
    const float inv_t = 1.0f / TEMP_;
    const float ds = du / fmaxf(sqrtf(uu), EPS_) * inv_t;
    const float dn = dv / fmaxf(sqrtf(vv), EPS_) * inv_t;
    float s1 = ds;
    float s2 = __expf(ds) + 3.0f * __expf(dn);

    // ---- combine the wave's 4 j's (cross-group butterfly) ----
    s1 += __shfl_xor(s1, 16, 64); s1 += __shfl_xor(s1, 32, 64);
    s2 += __shfl_xor(s2, 16, 64); s2 += __shfl_xor(s2, 32, 64);

    __shared__ float p1[4], p2[4];
    if (lane == 0) { p1[wave] = s1; p2[wave] = s2; }
    __syncthreads();
    if (tid == 0) {
        part[blk * 2 + 0] = p1[0] + p1[1] + p1[2] + p1[3];
        part[blk * 2 + 1] = p2[0] + p2[1] + p2[2] + p2[3];
    }
}

// ---------------------------------------------------------------------------
// k_final: thread i combines its 8 group-partials, computes
// contrib_i = (1/B) * sum_j d_self - log(denom_i), reduces over i.
// ---------------------------------------------------------------------------
__global__ __launch_bounds__(128) void k_final(const float* __restrict__ part,
                                               float* __restrict__ out) {
    const int i = threadIdx.x;
    float s1 = 0.0f, s2 = 0.0f;
#pragma unroll
    for (int q = 0; q < 8; ++q) {
        s1 += part[(i * 8 + q) * 2 + 0];
        s2 += part[(i * 8 + q) * 2 + 1];
    }
    float c = s1 * (1.0f / B_) - __logf(s2);
#pragma unroll
    for (int o = 1; o < 64; o <<= 1) c += __shfl_xor(c, o, 64);
    __shared__ float wsum[2];
    const int wave = i >> 6, lane = i & 63;
    if (lane == 0) wsum[wave] = c;
    __syncthreads();
    if (i == 0) out[0] = -(wsum[0] + wsum[1]) * (1.0f / B_);
}

extern "C" void kernel_launch(void* const* d_in, const int* in_sizes, int n_in,
                              void* d_out, int out_size, void* d_ws, size_t ws_size,
                              hipStream_t stream) {
    const float* feat = (const float*)d_in[0];
    float* part = (float*)d_ws;              // 1024*2 floats
    float* out = (float*)d_out;

    k_pairs<<<NBLK_, 256, 0, stream>>>(feat, part);
    k_final<<<1, 128, 0, stream>>>(part, out);
}

// Round 8
// 19.831 us; speedup vs baseline: 1.2121x; 1.0387x over previous
//
#include <hip/hip_runtime.h>
#include <math.h>

#define B_ 128
#define K_ 2048
#define TEMP_ 0.07f
#define EPS_ 1e-12f
#define NBLK_ 1024   // 128 i * 8 j-groups

// Packed fp32 (CDNA2+ dual-FP32): one instr = 2 fp32 ops/lane.
typedef float pf2 __attribute__((ext_vector_type(2)));

__device__ __forceinline__ pf2 pk_mul(pf2 a, pf2 b) {
    pf2 d;
    asm("v_pk_mul_f32 %0, %1, %2" : "=v"(d) : "v"(a), "v"(b));
    return d;
}
__device__ __forceinline__ pf2 pk_fma(pf2 a, pf2 b, pf2 c) {
    pf2 d;
    asm("v_pk_fma_f32 %0, %1, %2, %3" : "=v"(d) : "v"(a), "v"(b), "v"(c));
    return d;
}

// ---------------------------------------------------------------------------
// k_pairs v8: v7 structure (16-lane group per j, two-pass direct v-form)
// with the inner loops rewritten in packed fp32 (v_pk_fma_f32/v_pk_mul_f32):
// 8 packed instrs per 2 elements in pass 2 (was 18 scalar), 1 per 2 in pass 1.
//
// Math per component identical to v7:
//   a = x_i/||x_i||, g = 1+a^3 (LDS);  c = 1/max(||b||,eps)  [pass 1]
//   w = b*g: du=S(aw), uu=S(w^2);  p=a*b, q=p^2, v=c*q+b: dv=S(av), vv=S(v^2)
//   ds = du/max(sqrt(uu),eps)/T;   dn = dv/max(sqrt(vv),eps)/T
// Partials per (i,jg): sum_j ds, sum_j (e^ds + 3 e^dn).
// ---------------------------------------------------------------------------
__global__ __launch_bounds__(256, 4) void k_pairs(const float* __restrict__ feat,
                                                  float* __restrict__ part) {
    const int blk = blockIdx.x;
    const int i = blk >> 3;
    const int jg = blk & 7;
    const int tid = threadIdx.x;
    const int wave = tid >> 6, lane = tid & 63;
    const int s = lane & 15;      // sublane within 16-lane group
    const int grp = lane >> 4;    // group 0..3 -> which j

    __shared__ float sa[K_];
    __shared__ float sg[K_];
    __shared__ float wsum[4];

    // ---- stage i-row: block-local norm, then a and g=1+a^3 into LDS ----
    {
        const float4* fi4 = reinterpret_cast<const float4*>(feat + (size_t)i * K_);
        float4 v0 = fi4[tid];
        float4 v1 = fi4[tid + 256];
        float ss = v0.x * v0.x + v0.y * v0.y + v0.z * v0.z + v0.w * v0.w
                 + v1.x * v1.x + v1.y * v1.y + v1.z * v1.z + v1.w * v1.w;
#pragma unroll
        for (int o = 1; o < 64; o <<= 1) ss += __shfl_xor(ss, o, 64);
        if (lane == 0) wsum[wave] = ss;
        __syncthreads();
        const float tot = wsum[0] + wsum[1] + wsum[2] + wsum[3];
        const float rn = 1.0f / fmaxf(sqrtf(tot), EPS_);

        float4* a4w = reinterpret_cast<float4*>(sa);
        float4* g4w = reinterpret_cast<float4*>(sg);
#define STAGE(V, IDX)                                                   \
        {                                                               \
            float4 a, g;                                                \
            a.x = (V).x * rn; a.y = (V).y * rn;                         \
            a.z = (V).z * rn; a.w = (V).w * rn;                         \
            g.x = 1.0f + a.x * a.x * a.x; g.y = 1.0f + a.y * a.y * a.y; \
            g.z = 1.0f + a.z * a.z * a.z; g.w = 1.0f + a.w * a.w * a.w; \
            a4w[IDX] = a; g4w[IDX] = g;                                 \
        }
        STAGE(v0, tid)
        STAGE(v1, tid + 256)
#undef STAGE
    }
    __syncthreads();

    const int j = jg * 16 + wave * 4 + grp;
    const float4* bj = reinterpret_cast<const float4*>(feat + (size_t)j * K_);
    const float4* a4 = reinterpret_cast<const float4*>(sa);
    const float4* g4 = reinterpret_cast<const float4*>(sg);

    // ---- pass 1: sbb (packed) ----
    pf2 sbb2 = {0.f, 0.f};
#pragma unroll 8
    for (int c = 0; c < 32; ++c) {
        const float4 b = bj[c * 16 + s];
        pf2 b01; b01.x = b.x; b01.y = b.y;
        pf2 b23; b23.x = b.z; b23.y = b.w;
        sbb2 = pk_fma(b01, b01, sbb2);
        sbb2 = pk_fma(b23, b23, sbb2);
    }
    float sbb = sbb2.x + sbb2.y;
#pragma unroll
    for (int o = 1; o < 16; o <<= 1) sbb += __shfl_xor(sbb, o, 64);
    const float cc = 1.0f / fmaxf(sqrtf(sbb), EPS_);
    pf2 cc2; cc2.x = cc; cc2.y = cc;

    // ---- pass 2: du, uu, dv, vv (packed; v = cc*q + b formed directly) ----
    pf2 du01 = {0.f, 0.f}, du23 = {0.f, 0.f};
    pf2 uu01 = {0.f, 0.f}, uu23 = {0.f, 0.f};
    pf2 dv01 = {0.f, 0.f}, dv23 = {0.f, 0.f};
    pf2 vv01 = {0.f, 0.f}, vv23 = {0.f, 0.f};
#pragma unroll 8
    for (int c = 0; c < 32; ++c) {
        const int idx = c * 16 + s;        // same for all 4 groups: LDS broadcast
        const float4 a = a4[idx];
        const float4 g = g4[idx];
        const float4 b = bj[idx];
        pf2 a01; a01.x = a.x; a01.y = a.y;
        pf2 a23; a23.x = a.z; a23.y = a.w;
        pf2 g01; g01.x = g.x; g01.y = g.y;
        pf2 g23; g23.x = g.z; g23.y = g.w;
        pf2 b01; b01.x = b.x; b01.y = b.y;
        pf2 b23; b23.x = b.z; b23.y = b.w;

        const pf2 w01 = pk_mul(b01, g01);
        const pf2 w23 = pk_mul(b23, g23);
        du01 = pk_fma(a01, w01, du01);
        du23 = pk_fma(a23, w23, du23);
        uu01 = pk_fma(w01, w01, uu01);
        uu23 = pk_fma(w23, w23, uu23);
        const pf2 p01 = pk_mul(a01, b01);
        const pf2 p23 = pk_mul(a23, b23);
        const pf2 q01 = pk_mul(p01, p01);
        const pf2 q23 = pk_mul(p23, p23);
        const pf2 v01 = pk_fma(cc2, q01, b01);
        const pf2 v23 = pk_fma(cc2, q23, b23);
        dv01 = pk_fma(a01, v01, dv01);
        dv23 = pk_fma(a23, v23, dv23);
        vv01 = pk_fma(v01, v01, vv01);
        vv23 = pk_fma(v23, v23, vv23);
    }
    float du = (du01.x + du01.y) + (du23.x + du23.y);
    float uu = (uu01.x + uu01.y) + (uu23.x + uu23.y);
    float dv = (dv01.x + dv01.y) + (dv23.x + dv23.y);
    float vv = (vv01.x + vv01.y) + (vv23.x + vv23.y);

    // ---- 4-step butterfly within the 16-lane group (4 sums) ----
#pragma unroll
    for (int o = 1; o < 16; o <<= 1) {
        du += __shfl_xor(du, o, 64);
        uu += __shfl_xor(uu, o, 64);
        dv += __shfl_xor(dv, o, 64);
        vv += __shfl_xor(vv, o, 64);
    }

    // ---- per-j epilogue ----
    const float inv_t = 1.0f / TEMP_;
    const float ds = du / fmaxf(sqrtf(uu), EPS_) * inv_t;
    const float dn = dv / fmaxf(sqrtf(vv), EPS_) * inv_t;
    float s1 = ds;
    float s2 = __expf(ds) + 3.0f * __expf(dn);

    // ---- combine the wave's 4 j's (cross-group butterfly) ----
    s1 += __shfl_xor(s1, 16, 64); s1 += __shfl_xor(s1, 32, 64);
    s2 += __shfl_xor(s2, 16, 64); s2 += __shfl_xor(s2, 32, 64);

    __shared__ float p1[4], p2[4];
    if (lane == 0) { p1[wave] = s1; p2[wave] = s2; }
    __syncthreads();
    if (tid == 0) {
        part[blk * 2 + 0] = p1[0] + p1[1] + p1[2] + p1[3];
        part[blk * 2 + 1] = p2[0] + p2[1] + p2[2] + p2[3];
    }
}

// ---------------------------------------------------------------------------
// k_final: thread i combines its 8 group-partials, computes
// contrib_i = (1/B) * sum_j d_self - log(denom_i), reduces over i.
// ---------------------------------------------------------------------------
__global__ __launch_bounds__(128) void k_final(const float* __restrict__ part,
                                               float* __restrict__ out) {
    const int i = threadIdx.x;
    float s1 = 0.0f, s2 = 0.0f;
#pragma unroll
    for (int q = 0; q < 8; ++q) {
        s1 += part[(i * 8 + q) * 2 + 0];
        s2 += part[(i * 8 + q) * 2 + 1];
    }
    float c = s1 * (1.0f / B_) - __logf(s2);
#pragma unroll
    for (int o = 1; o < 64; o <<= 1) c += __shfl_xor(c, o, 64);
    __shared__ float wsum[2];
    const int wave = i >> 6, lane = i & 63;
    if (lane == 0) wsum[wave] = c;
    __syncthreads();
    if (i == 0) out[0] = -(wsum[0] + wsum[1]) * (1.0f / B_);
}

extern "C" void kernel_launch(void* const* d_in, const int* in_sizes, int n_in,
                              void* d_out, int out_size, void* d_ws, size_t ws_size,
                              hipStream_t stream) {
    const float* feat = (const float*)d_in[0];
    float* part = (float*)d_ws;              // 1024*2 floats
    float* out = (float*)d_out;

    k_pairs<<<NBLK_, 256, 0, stream>>>(feat, part);
    k_final<<<1, 128, 0, stream>>>(part, out);
}